// Round 2
// baseline (378.739 us; speedup 1.0000x reference)
//
#include <hip/hip_runtime.h>

typedef _Float16 f16;
typedef _Float16 f16x8 __attribute__((ext_vector_type(8)));
typedef __fp16   h16x2 __attribute__((ext_vector_type(2)));
typedef float    f32x4 __attribute__((ext_vector_type(4)));

constexpr int NB = 32;      // batch
constexpr int NN = 1024;    // tokens (M)
constexpr int KK = 1024;    // fin (K)
constexpr int MO = 1024;    // fout (N)
constexpr int BM = 128, BN = 128, BK = 32;
constexpr int LDA = 40;     // padded LDS row stride in f16 (80 B, 16B-aligned)

__global__ __launch_bounds__(256)
void cond_linear_kernel(const float* __restrict__ x,
                        const int* __restrict__ task_id,
                        const float* __restrict__ W,
                        float* __restrict__ out) {
    __shared__ __align__(16) f16 As[BM * LDA];
    __shared__ __align__(16) f16 Bs[BN * LDA];

    const int bid   = blockIdx.x;
    const int batch = bid >> 6;        // 64 tiles per batch
    const int tile  = bid & 63;
    const int tm    = tile >> 3;       // row-tile (M)
    const int tn    = tile & 7;        // col-tile (FOUT)

    const int tid  = threadIdx.x;
    const int task = task_id[batch];

    const float* xb = x + (size_t)batch * NN * KK + (size_t)(tm * BM) * KK;
    const float* wb = W + (size_t)task * MO * KK + (size_t)(tn * BN) * KK;

    // staging: 512 chunks of 8 floats cover one 128x32 tile; each thread: 2 chunks of A, 2 of B
    const int c0 = tid, c1 = tid + 256;
    const int r0 = c0 >> 2, ko0 = (c0 & 3) * 8;
    const int r1 = c1 >> 2, ko1 = (c1 & 3) * 8;

    const float* pa0 = xb + r0 * KK + ko0;
    const float* pa1 = xb + r1 * KK + ko1;
    const float* pb0 = wb + r0 * KK + ko0;
    const float* pb1 = wb + r1 * KK + ko1;

    f32x4 ra[4], rb[4];

    auto load_tile = [&](int k0) {
        ra[0] = *(const f32x4*)(pa0 + k0);
        ra[1] = *(const f32x4*)(pa0 + k0 + 4);
        ra[2] = *(const f32x4*)(pa1 + k0);
        ra[3] = *(const f32x4*)(pa1 + k0 + 4);
        rb[0] = *(const f32x4*)(pb0 + k0);
        rb[1] = *(const f32x4*)(pb0 + k0 + 4);
        rb[2] = *(const f32x4*)(pb1 + k0);
        rb[3] = *(const f32x4*)(pb1 + k0 + 4);
    };

    auto cvt8 = [](const f32x4& lo, const f32x4& hi) -> f16x8 {
        union { h16x2 h[4]; f16x8 v; } u;
        u.h[0] = __builtin_amdgcn_cvt_pkrtz(lo[0], lo[1]);
        u.h[1] = __builtin_amdgcn_cvt_pkrtz(lo[2], lo[3]);
        u.h[2] = __builtin_amdgcn_cvt_pkrtz(hi[0], hi[1]);
        u.h[3] = __builtin_amdgcn_cvt_pkrtz(hi[2], hi[3]);
        return u.v;
    };

    auto store_lds = [&]() {
        *(f16x8*)&As[r0 * LDA + ko0] = cvt8(ra[0], ra[1]);
        *(f16x8*)&As[r1 * LDA + ko1] = cvt8(ra[2], ra[3]);
        *(f16x8*)&Bs[r0 * LDA + ko0] = cvt8(rb[0], rb[1]);
        *(f16x8*)&Bs[r1 * LDA + ko1] = cvt8(rb[2], rb[3]);
    };

    // wave layout: 2x2 waves, each computes 64x64 via 4x4 MFMA 16x16 tiles
    const int lane = tid & 63;
    const int wave = tid >> 6;
    const int wr   = (wave >> 1) * 64;
    const int wc   = (wave & 1) * 64;
    const int lm   = lane & 15;   // fragment row/col within 16
    const int lq   = lane >> 4;   // quad: k-offset group

    f32x4 acc[4][4] = {};

    const f16* pAs = &As[(wr + lm) * LDA + lq * 8];
    const f16* pBs = &Bs[(wc + lm) * LDA + lq * 8];

    load_tile(0);
    for (int ks = 0; ks < KK / BK; ++ks) {
        store_lds();
        __syncthreads();
        if (ks + 1 < KK / BK) load_tile((ks + 1) * BK);

        f16x8 af[4], bf[4];
        #pragma unroll
        for (int i = 0; i < 4; ++i) af[i] = *(const f16x8*)(pAs + i * 16 * LDA);
        #pragma unroll
        for (int j = 0; j < 4; ++j) bf[j] = *(const f16x8*)(pBs + j * 16 * LDA);

        #pragma unroll
        for (int i = 0; i < 4; ++i)
            #pragma unroll
            for (int j = 0; j < 4; ++j)
                acc[i][j] = __builtin_amdgcn_mfma_f32_16x16x32_f16(af[i], bf[j], acc[i][j], 0, 0, 0);

        __syncthreads();
    }

    // epilogue: C/D layout col=lane&15, row=(lane>>4)*4+reg  [m89-verified]
    float* ob = out + (size_t)batch * NN * MO + (size_t)(tm * BM) * MO + (tn * BN);
    #pragma unroll
    for (int i = 0; i < 4; ++i) {
        #pragma unroll
        for (int j = 0; j < 4; ++j) {
            const int row0 = wr + i * 16 + lq * 4;
            const int col  = wc + j * 16 + lm;
            #pragma unroll
            for (int r = 0; r < 4; ++r)
                ob[(size_t)(row0 + r) * MO + col] = acc[i][j][r];
        }
    }

    // second tuple output: task_id as float, at offset NB*NN*MO
    if (tile == 0 && tid == 0)
        out[(size_t)NB * NN * MO + batch] = (float)task;
}

extern "C" void kernel_launch(void* const* d_in, const int* in_sizes, int n_in,
                              void* d_out, int out_size, void* d_ws, size_t ws_size,
                              hipStream_t stream) {
    const float* x       = (const float*)d_in[0];
    const int*   task_id = (const int*)d_in[1];
    const float* W       = (const float*)d_in[2];
    float*       out     = (float*)d_out;

    dim3 grid(NB * (NN / BM) * (MO / BN));  // 32 * 8 * 8 = 2048
    dim3 block(256);
    cond_linear_kernel<<<grid, block, 0, stream>>>(x, task_id, W, out);
}

// Round 3
// 372.157 us; speedup vs baseline: 1.0177x; 1.0177x over previous
//
#include <hip/hip_runtime.h>

typedef _Float16 f16;
typedef _Float16 f16x8 __attribute__((ext_vector_type(8)));
typedef __fp16   h16x2 __attribute__((ext_vector_type(2)));
typedef float    f32x4 __attribute__((ext_vector_type(4)));

constexpr int NB = 32, NN = 1024, KK = 1024, MO = 1024;
constexpr int BM = 128, BN = 128, BK = 32;
constexpr int LDA = 40;          // padded LDS row stride in f16 (80 B)
constexpr int NSTEP = KK / BK;   // 32

__global__ __launch_bounds__(256, 2)
void cond_linear_kernel(const float* __restrict__ x,
                        const int* __restrict__ task_id,
                        const float* __restrict__ W,
                        float* __restrict__ out) {
    __shared__ __align__(16) f16 As[2][BM * LDA];
    __shared__ __align__(16) f16 Bs[2][BN * LDA];

    const int bid   = blockIdx.x;
    const int batch = bid >> 6;
    const int tile  = bid & 63;
    // XCD swizzle: bid%8 == tile&7 == tm -> all 8 tn-tiles sharing an x-band
    // land on the same XCD's L2 (round-robin dispatch assumption; perf-only).
    const int tm = tile & 7;
    const int tn = tile >> 3;

    const int tid  = threadIdx.x;
    const int task = task_id[batch];

    const float* xb = x + (size_t)batch * NN * KK + (size_t)(tm * BM) * KK;
    const float* wb = W + (size_t)task * MO * KK + (size_t)(tn * BN) * KK;

    // staging: 512 chunks of 8 floats cover one 128x32 tile; each thread: 2 A + 2 B chunks
    const int c0 = tid, c1 = tid + 256;
    const int r0 = c0 >> 2, ko0 = (c0 & 3) * 8;
    const int r1 = c1 >> 2, ko1 = (c1 & 3) * 8;

    const float* pa0 = xb + r0 * KK + ko0;
    const float* pa1 = xb + r1 * KK + ko1;
    const float* pb0 = wb + r0 * KK + ko0;
    const float* pb1 = wb + r1 * KK + ko1;

    // two register tile-sets in flight (prefetch distance 2)
    f32x4 ra0[4], rb0[4], ra1[4], rb1[4];

    auto load0 = [&](int k0) {
        ra0[0] = *(const f32x4*)(pa0 + k0); ra0[1] = *(const f32x4*)(pa0 + k0 + 4);
        ra0[2] = *(const f32x4*)(pa1 + k0); ra0[3] = *(const f32x4*)(pa1 + k0 + 4);
        rb0[0] = *(const f32x4*)(pb0 + k0); rb0[1] = *(const f32x4*)(pb0 + k0 + 4);
        rb0[2] = *(const f32x4*)(pb1 + k0); rb0[3] = *(const f32x4*)(pb1 + k0 + 4);
    };
    auto load1 = [&](int k0) {
        ra1[0] = *(const f32x4*)(pa0 + k0); ra1[1] = *(const f32x4*)(pa0 + k0 + 4);
        ra1[2] = *(const f32x4*)(pa1 + k0); ra1[3] = *(const f32x4*)(pa1 + k0 + 4);
        rb1[0] = *(const f32x4*)(pb0 + k0); rb1[1] = *(const f32x4*)(pb0 + k0 + 4);
        rb1[2] = *(const f32x4*)(pb1 + k0); rb1[3] = *(const f32x4*)(pb1 + k0 + 4);
    };

    auto cvt8 = [](const f32x4& lo, const f32x4& hi) -> f16x8 {
        union { h16x2 h[4]; f16x8 v; } u;
        u.h[0] = __builtin_amdgcn_cvt_pkrtz(lo[0], lo[1]);
        u.h[1] = __builtin_amdgcn_cvt_pkrtz(lo[2], lo[3]);
        u.h[2] = __builtin_amdgcn_cvt_pkrtz(hi[0], hi[1]);
        u.h[3] = __builtin_amdgcn_cvt_pkrtz(hi[2], hi[3]);
        return u.v;
    };

    auto store0 = [&](int buf) {
        *(f16x8*)&As[buf][r0 * LDA + ko0] = cvt8(ra0[0], ra0[1]);
        *(f16x8*)&As[buf][r1 * LDA + ko1] = cvt8(ra0[2], ra0[3]);
        *(f16x8*)&Bs[buf][r0 * LDA + ko0] = cvt8(rb0[0], rb0[1]);
        *(f16x8*)&Bs[buf][r1 * LDA + ko1] = cvt8(rb0[2], rb0[3]);
    };
    auto store1 = [&](int buf) {
        *(f16x8*)&As[buf][r0 * LDA + ko0] = cvt8(ra1[0], ra1[1]);
        *(f16x8*)&As[buf][r1 * LDA + ko1] = cvt8(ra1[2], ra1[3]);
        *(f16x8*)&Bs[buf][r0 * LDA + ko0] = cvt8(rb1[0], rb1[1]);
        *(f16x8*)&Bs[buf][r1 * LDA + ko1] = cvt8(rb1[2], rb1[3]);
    };

    // wave layout: 2x2 waves, each 64x64 via 4x4 MFMA 16x16 tiles
    const int lane = tid & 63;
    const int wave = tid >> 6;
    const int wr   = (wave >> 1) * 64;
    const int wc   = (wave & 1) * 64;
    const int lm   = lane & 15;
    const int lq   = lane >> 4;

    f32x4 acc[4][4] = {};

    const int fa_off = (wr + lm) * LDA + lq * 8;
    const int fb_off = (wc + lm) * LDA + lq * 8;

    auto compute = [&](int buf) {
        f16x8 af[4], bf[4];
        #pragma unroll
        for (int i = 0; i < 4; ++i) af[i] = *(const f16x8*)&As[buf][fa_off + i * 16 * LDA];
        #pragma unroll
        for (int j = 0; j < 4; ++j) bf[j] = *(const f16x8*)&Bs[buf][fb_off + j * 16 * LDA];
        #pragma unroll
        for (int i = 0; i < 4; ++i)
            #pragma unroll
            for (int j = 0; j < 4; ++j)
                acc[i][j] = __builtin_amdgcn_mfma_f32_16x16x32_f16(af[i], bf[j], acc[i][j], 0, 0, 0);
    };

    // prologue: G(0), G(1) in flight; stage G(0) into LDS buf0
    load0(0);
    load1(BK);
    store0(0);
    __syncthreads();

    // steady state, manually unrolled x2 so register slots are compile-time.
    // iter ks: issue G(ks+2) into the slot freed last iter; compute buf ks&1;
    // stage G(ks+1) into buf (ks+1)&1; single barrier.
    for (int ks = 0; ks < NSTEP; ks += 2) {
        // even step: compute buf0, slot0 free -> load G(ks+2), store slot1 -> buf1
        if (ks + 2 < NSTEP) load0((ks + 2) * BK);
        compute(0);
        store1(1);
        __syncthreads();
        // odd step: compute buf1, slot1 free -> load G(ks+3), store slot0 -> buf0
        if (ks + 3 < NSTEP) load1((ks + 3) * BK);
        compute(1);
        if (ks + 2 < NSTEP) store0(0);
        __syncthreads();
    }

    // epilogue: C/D layout col=lane&15, row=(lane>>4)*4+reg  [m89-verified]
    float* ob = out + (size_t)batch * NN * MO + (size_t)(tm * BM) * MO + (tn * BN);
    #pragma unroll
    for (int i = 0; i < 4; ++i) {
        #pragma unroll
        for (int j = 0; j < 4; ++j) {
            const int row0 = wr + i * 16 + lq * 4;
            const int col  = wc + j * 16 + lm;
            #pragma unroll
            for (int r = 0; r < 4; ++r)
                ob[(size_t)(row0 + r) * MO + col] = acc[i][j][r];
        }
    }

    // second tuple output: task_id as float, at offset NB*NN*MO
    if (tile == 0 && tid == 0)
        out[(size_t)NB * NN * MO + batch] = (float)task;
}

extern "C" void kernel_launch(void* const* d_in, const int* in_sizes, int n_in,
                              void* d_out, int out_size, void* d_ws, size_t ws_size,
                              hipStream_t stream) {
    const float* x       = (const float*)d_in[0];
    const int*   task_id = (const int*)d_in[1];
    const float* W       = (const float*)d_in[2];
    float*       out     = (float*)d_out;

    dim3 grid(NB * (NN / BM) * (MO / BN));  // 2048
    dim3 block(256);
    cond_linear_kernel<<<grid, block, 0, stream>>>(x, task_id, W, out);
}